// Round 7
// baseline (552.412 us; speedup 1.0000x reference)
//
#include <hip/hip_runtime.h>
#include <hip/hip_fp16.h>

constexpr int KC   = 128;    // channels
constexpr int NBLK = 256;    // partition blocks
constexpr int CAPA = 8192;   // per-block edge chunk cap (chunk = 2M/256 = 7813)
constexpr int CAPB = 4608;   // per-bucket edge cap (mean 3200, sd 57 -> +24 sigma)

using half8  = __attribute__((ext_vector_type(8))) _Float16;
using float4v = __attribute__((ext_vector_type(4))) float;

// ---------------------------------------------------------------- helpers
__device__ __forceinline__ unsigned fkey(float s) {
  unsigned u = __float_as_uint(s);
  return (u & 0x80000000u) ? ~u : (u | 0x80000000u);
}

// block-wide in-place exclusive scan of arr[0..M), 256 threads, M<=1024
__device__ __forceinline__ void block_exscan(unsigned* arr, int M, unsigned* tmp4) {
  int t = threadIdx.x;
  const int K = (M + 255) >> 8;
  unsigned loc[4];
  unsigned s = 0;
  int base = t * K;
#pragma unroll
  for (int k = 0; k < 4; ++k) {
    if (k < K) {
      unsigned v = (base + k < M) ? arr[base + k] : 0;
      loc[k] = s; s += v;
    }
  }
  unsigned inc = s;
#pragma unroll
  for (int off = 1; off < 64; off <<= 1) {
    unsigned u = __shfl_up(inc, off, 64);
    if ((t & 63) >= off) inc += u;
  }
  int w = t >> 6;
  if ((t & 63) == 63) tmp4[w] = inc;
  __syncthreads();
  unsigned wbase = 0;
  if (w > 0) wbase += tmp4[0];
  if (w > 1) wbase += tmp4[1];
  if (w > 2) wbase += tmp4[2];
  unsigned exc = wbase + inc - s;
  __syncthreads();
#pragma unroll
  for (int k = 0; k < 4; ++k)
    if (k < K && base + k < M) arr[base + k] = exc + loc[k];
  __syncthreads();
}

// ==== FUSED: dual bucket counts (src+dst, LDS only) + scores + x16 =======
// No global scattered atomics. Scores stream hides the edge-read latency.
__global__ __launch_bounds__(256) void k_cnt2(const int* __restrict__ eui,
                                              const int* __restrict__ eiu,
                                              const float* __restrict__ xu,
                                              const float* __restrict__ xi,
                                              const float* __restrict__ pu,
                                              const float* __restrict__ pi,
                                              float* __restrict__ scores,
                                              unsigned* __restrict__ hist_sc,
                                              __half* __restrict__ x16,
                                              unsigned* __restrict__ cnts,
                                              int E, int N, int NB, int chunk, int NTOT) {
  __shared__ unsigned hD[640], hS[640];
  int t = threadIdx.x, blk = blockIdx.x;
  for (int b = t; b < NB; b += 256) { hD[b] = 0; hS[b] = 0; }
  __syncthreads();
  int lo = blk * chunk, hi = min(2 * E, lo + chunk);
  for (int i = lo + t; i < hi; i += 256) {
    int rel = i >= E;
    const int* e = rel ? eiu : eui;
    int j = i - rel * E;
    int src_g = rel * N + e[j];
    int dst_g = rel * N + e[E + j];
    atomicAdd(&hD[dst_g >> 8], 1u);
    atomicAdd(&hS[src_g >> 8], 1u);
  }
  __syncthreads();
  for (int b = t; b < NB; b += 256) {
    cnts[(size_t)blk * NB + b] = hD[b];
    cnts[(size_t)NTOT + (size_t)blk * NB + b] = hS[b];
  }
  // ---- scores + fp16 copy, grid-stride: 1024 waves over 2N rows ----
  int wid = blk * 4 + (t >> 6), lane = t & 63;
  for (int gw = wid; gw < 2 * N; gw += NBLK * 4) {
    int rel = gw >= N;
    int r = gw - rel * N;
    const float* x = rel ? xi : xu;
    const float* p = rel ? pi : pu;
    float2 xv = ((const float2*)(x + (size_t)r * KC))[lane];
    float2 pv = ((const float2*)p)[lane];
    *(__half2*)(x16 + (size_t)gw * KC + lane * 2) = __floats2half2_rn(xv.x, xv.y);
    float s = xv.x * pv.x + xv.y * pv.y;
#pragma unroll
    for (int off = 32; off; off >>= 1) s += __shfl_down(s, off, 64);
    if (lane == 0) {
      scores[gw] = s;
      atomicAdd(&hist_sc[rel * 65536 + (fkey(s) >> 16)], 1u);
    }
  }
}

// ---- threshold bin (blockIdx = relation) --------------------------------
__global__ void k_thresh(const unsigned* __restrict__ hist, unsigned* __restrict__ ctrl) {
  const unsigned* h = hist + blockIdx.x * 65536;
  unsigned* c = ctrl + blockIdx.x * 8;
  __shared__ unsigned csum[1024];
  __shared__ int s_chunk;
  __shared__ unsigned s_above;
  int t = threadIdx.x;
  unsigned s = 0;
  int hi = 65536 - 64 * t;
  for (int b = hi - 64; b < hi; ++b) s += h[b];
  csum[t] = s;
  __syncthreads();
  for (int off = 1; off < 1024; off <<= 1) {
    unsigned add = (t >= off) ? csum[t - off] : 0;
    __syncthreads();
    csum[t] += add;
    __syncthreads();
  }
  unsigned above = (t == 0) ? 0u : csum[t - 1];
  if (csum[t] >= 128u && above < 128u) { s_chunk = t; s_above = above; }
  __syncthreads();
  int chi = 65536 - 64 * s_chunk;
  __shared__ unsigned bs[64];
  if (t < 64) bs[t] = h[chi - 1 - t];
  __syncthreads();
  if (t < 64) {
    unsigned v = bs[t], cum = v;
#pragma unroll
    for (int off = 1; off < 64; off <<= 1) {
      unsigned u = __shfl_up(cum, off, 64);
      if (t >= off) cum += u;
    }
    unsigned prev = cum - v;
    if (s_above + cum >= 128u && s_above + prev < 128u)
      c[0] = (unsigned)(chi - 1 - t);
  }
}

// ---- compact candidates -------------------------------------------------
__global__ void k_compact(const float* __restrict__ scores, unsigned* __restrict__ ctrl,
                          int* __restrict__ cand_idx, float* __restrict__ cand_val, int N) {
  int i = blockIdx.x * blockDim.x + threadIdx.x;
  if (i >= 2 * N) return;
  int rel = i >= N;
  float s = scores[i];
  if ((fkey(s) >> 16) >= ctrl[rel * 8]) {
    unsigned pos = atomicAdd(&ctrl[rel * 8 + 1], 1u);
    if (pos < 2048u) {
      cand_idx[rel * 2048 + pos] = i - rel * N;
      cand_val[rel * 2048 + pos] = s;
    }
  }
}

// ---- exact rank among candidates ---------------------------------------
__global__ void k_topk(const unsigned* __restrict__ ctrl,
                       const int* __restrict__ cand_idx, const float* __restrict__ cand_val,
                       const float* __restrict__ pu, const float* __restrict__ pi,
                       int* __restrict__ top_idx, float* __restrict__ top_tanh) {
  __shared__ float vals[2048];
  __shared__ int   idxs[2048];
  __shared__ float red[128];
  int rel = blockIdx.x, t = threadIdx.x;
  const float* p = rel ? pi : pu;
  int n = (int)ctrl[rel * 8 + 1]; if (n > 2048) n = 2048;
  for (int i = t; i < n; i += 128) {
    vals[i] = cand_val[rel * 2048 + i];
    idxs[i] = cand_idx[rel * 2048 + i];
  }
  float pv = p[t];
  red[t] = pv * pv;
  __syncthreads();
  for (int off = 64; off; off >>= 1) { if (t < off) red[t] += red[t + off]; __syncthreads(); }
  float pn = sqrtf(red[0]) + 1e-16f;
  for (int c = t; c < n; c += 128) {
    float v = vals[c]; int id = idxs[c];
    int rank = 0;
    for (int j = 0; j < n; ++j) {
      float vj = vals[j];
      rank += (vj > v) || (vj == v && idxs[j] < id);
    }
    if (rank < KC) {
      top_idx[rel * KC + rank] = id;
      top_tanh[rel * KC + rank] = tanhf(v / pn);
    }
  }
}

// ---- X_tilde ------------------------------------------------------------
__global__ void k_xtilde(const float* __restrict__ xu, const float* __restrict__ xi,
                         const int* __restrict__ top_idx, const float* __restrict__ top_tanh,
                         float* __restrict__ Xt) {
  int t = blockIdx.x * blockDim.x + threadIdx.x;
  int rel = t >> 14;
  int c = (t >> 7) & 127, j = t & 127;
  const float* x = rel ? xi : xu;
  Xt[t] = x[(size_t)top_idx[rel * KC + c] * KC + j] * top_tanh[rel * KC + c];
}

// ---- GRU step -> evolved weight, stored fp16 TRANSPOSED -----------------
__global__ void k_gru(const float* __restrict__ Xt,
                      const float* __restrict__ W0u, const float* __restrict__ W0i,
                      const float* __restrict__ Wihu, const float* __restrict__ Wihi,
                      const float* __restrict__ Whhu, const float* __restrict__ Whhi,
                      const float* __restrict__ bihu, const float* __restrict__ bihi,
                      const float* __restrict__ bhhu, const float* __restrict__ bhhi,
                      __half* __restrict__ Wt) {
  __shared__ float xt[KC], w0[KC];
  int rel = blockIdx.x >> 7, c = blockIdx.x & 127, k = threadIdx.x;
  const float* W0  = rel ? W0i  : W0u;
  const float* Wih = rel ? Wihi : Wihu;
  const float* Whh = rel ? Whhi : Whhu;
  const float* bih = rel ? bihi : bihu;
  const float* bhh = rel ? bhhi : bhhu;
  xt[k] = Xt[rel * KC * KC + c * KC + k];
  w0[k] = W0[c * KC + k];
  __syncthreads();
  float gir = bih[k], giz = bih[KC + k], gin = bih[2 * KC + k];
  float ghr = bhh[k], ghz = bhh[KC + k], ghn = bhh[2 * KC + k];
  const float* wr = Wih + (size_t)k * KC;
  const float* wz = Wih + (size_t)(KC + k) * KC;
  const float* wn = Wih + (size_t)(2 * KC + k) * KC;
  const float* vr = Whh + (size_t)k * KC;
  const float* vz = Whh + (size_t)(KC + k) * KC;
  const float* vn = Whh + (size_t)(2 * KC + k) * KC;
  for (int j = 0; j < KC; ++j) {
    float xj = xt[j], hj = w0[j];
    gir += xj * wr[j]; giz += xj * wz[j]; gin += xj * wn[j];
    ghr += hj * vr[j]; ghz += hj * vz[j]; ghn += hj * vn[j];
  }
  float r = 1.f / (1.f + expf(-(gir + ghr)));
  float z = 1.f / (1.f + expf(-(giz + ghz)));
  float nn = tanhf(gin + r * ghn);
  float w = (1.f - z) * nn + z * w0[k];
  Wt[(size_t)rel * KC * KC + (size_t)k * KC + c] = __float2half_rn(w);
}

// ==== scan: two independent segments (dst offsets | src offsets) =========
// segment length NTOT, SCB blocks each, bucket-major reorder on read.
__global__ void k_scan1(const unsigned* __restrict__ cnts, unsigned* __restrict__ sc,
                        unsigned* __restrict__ bsum, int NTOT, int NB, int SCB) {
  __shared__ unsigned sh[1024];
  int t = threadIdx.x;
  int seg = blockIdx.x / SCB, lb = blockIdx.x % SCB;
  int li = lb * 1024 + t;
  unsigned v = 0;
  if (li < NTOT) {
    int b = li >> 8, blk = li & (NBLK - 1);
    v = cnts[(size_t)seg * NTOT + (size_t)blk * NB + b];
  }
  sh[t] = v; __syncthreads();
  for (int off = 1; off < 1024; off <<= 1) {
    unsigned add = (t >= off) ? sh[t - off] : 0;
    __syncthreads();
    sh[t] += add;
    __syncthreads();
  }
  if (li < NTOT) sc[(size_t)seg * NTOT + li] = sh[t] - v;
  if (t == 1023) bsum[blockIdx.x] = sh[1023];
}

__global__ void k_scan2(unsigned* __restrict__ bsum, int nb) {
  __shared__ unsigned sh[256];
  unsigned* bs = bsum + blockIdx.x * nb;
  int t = threadIdx.x;
  unsigned v = (t < nb) ? bs[t] : 0;
  sh[t] = v; __syncthreads();
  for (int off = 1; off < 256; off <<= 1) {
    unsigned add = (t >= off) ? sh[t - off] : 0;
    __syncthreads();
    sh[t] += add;
    __syncthreads();
  }
  if (t < nb) bs[t] = sh[t] - v;
}

__global__ void k_scan3(unsigned* __restrict__ sc, const unsigned* __restrict__ bsum,
                        int NTOT, int SCB) {
  int i = blockIdx.x * blockDim.x + threadIdx.x;
  if (i >= 2 * NTOT) return;
  int seg = i >= NTOT;
  int li = i - seg * NTOT;
  sc[i] += bsum[seg * SCB + (li >> 10)];
}

// ==== dst partition — block-local counting sort, coalesced write =========
__global__ __launch_bounds__(256) void k_part(const int* __restrict__ eui,
                                              const int* __restrict__ eiu,
                                              const unsigned* __restrict__ cnts,
                                              const unsigned* __restrict__ sc,
                                              unsigned* __restrict__ recs,
                                              int E, int N, int NB, int chunk) {
  __shared__ unsigned hist[640];
  __shared__ unsigned cur[640];
  __shared__ unsigned delta[640];
  __shared__ unsigned tmp4[4];
  __shared__ unsigned stage[CAPA];
  __shared__ unsigned short bkt16[CAPA];
  int t = threadIdx.x, blk = blockIdx.x;
  for (int b = t; b < NB; b += 256) hist[b] = cnts[(size_t)blk * NB + b];
  __syncthreads();
  int lo = blk * chunk, hi = min(2 * E, lo + chunk);
  block_exscan(hist, NB, tmp4);
  for (int b = t; b < NB; b += 256) cur[b] = hist[b];
  __syncthreads();
  for (int i = lo + t; i < hi; i += 256) {
    int rel = i >= E;
    const int* e = rel ? eiu : eui;
    int j = i - rel * E;
    int src_g = rel * N + e[j];
    int dst_g = rel * N + e[E + j];
    int b = dst_g >> 8;
    unsigned pos = atomicAdd(&cur[b], 1u);
    stage[pos] = (unsigned)src_g | ((unsigned)(dst_g & 255) << 18);
    bkt16[pos] = (unsigned short)b;
  }
  for (int b = t; b < NB; b += 256)
    delta[b] = sc[(size_t)b * NBLK + blk] - hist[b];
  __syncthreads();
  int cnt = hi - lo;
  for (int j = t; j < cnt; j += 256)
    recs[delta[bkt16[j]] + j] = stage[j];
}

// ==== src partition — byte records (only low 8 bits needed for degrees) ==
__global__ __launch_bounds__(256) void k_part_s(const int* __restrict__ eui,
                                                const int* __restrict__ eiu,
                                                const unsigned* __restrict__ cnts_s,
                                                const unsigned* __restrict__ sc_s,
                                                unsigned char* __restrict__ recs_s,
                                                int E, int N, int NB, int chunk) {
  __shared__ unsigned hist[640];
  __shared__ unsigned cur[640];
  __shared__ unsigned delta[640];
  __shared__ unsigned tmp4[4];
  __shared__ unsigned char stageB[CAPA];
  __shared__ unsigned short bkt16[CAPA];
  int t = threadIdx.x, blk = blockIdx.x;
  for (int b = t; b < NB; b += 256) hist[b] = cnts_s[(size_t)blk * NB + b];
  __syncthreads();
  int lo = blk * chunk, hi = min(2 * E, lo + chunk);
  block_exscan(hist, NB, tmp4);
  for (int b = t; b < NB; b += 256) cur[b] = hist[b];
  __syncthreads();
  for (int i = lo + t; i < hi; i += 256) {
    int rel = i >= E;
    const int* e = rel ? eiu : eui;
    int j = i - rel * E;
    int src_g = rel * N + e[j];
    int b = src_g >> 8;
    unsigned pos = atomicAdd(&cur[b], 1u);
    stageB[pos] = (unsigned char)(src_g & 255);
    bkt16[pos] = (unsigned short)b;
  }
  for (int b = t; b < NB; b += 256)
    delta[b] = sc_s[(size_t)b * NBLK + blk] - hist[b];
  __syncthreads();
  int cnt = hi - lo;
  for (int j = t; j < cnt; j += 256)
    recs_s[delta[bkt16[j]] + j] = stageB[j];
}

// ==== dst refine — per-bucket exact CSR + deg_dst/endp ===================
__global__ __launch_bounds__(256) void k_refine(const unsigned* __restrict__ sc,
                                                const unsigned* __restrict__ recs,
                                                int* __restrict__ ssrc,
                                                int* __restrict__ deg_dst,
                                                int* __restrict__ endp,
                                                int E, int NB, int N2) {
  __shared__ unsigned hist[256];
  __shared__ unsigned cur[256];
  __shared__ unsigned tmp4[4];
  __shared__ unsigned stage[CAPB];
  int b = blockIdx.x, t = threadIdx.x;
  int lo = (int)sc[(size_t)b * NBLK];
  int hi = (b + 1 < NB) ? (int)sc[(size_t)(b + 1) * NBLK] : 2 * E;
  int cnt = hi - lo; if (cnt > CAPB) cnt = CAPB;
  hist[t] = 0;
  __syncthreads();
  for (int j = t; j < cnt; j += 256)
    atomicAdd(&hist[recs[lo + j] >> 18], 1u);
  __syncthreads();
  unsigned h0 = hist[t];
  block_exscan(hist, 256, tmp4);
  int dst_g = b * 256 + t;
  if (dst_g < N2) {
    deg_dst[dst_g] = (int)h0;
    endp[dst_g] = lo + (int)(hist[t] + h0);
  }
  cur[t] = hist[t];
  __syncthreads();
  for (int j = t; j < cnt; j += 256) {
    unsigned rec = recs[lo + j];
    unsigned pos = atomicAdd(&cur[rec >> 18], 1u);
    stage[pos] = rec & 0x3FFFFu;
  }
  __syncthreads();
  for (int j = t; j < cnt; j += 256)
    ssrc[lo + j] = (int)stage[j];
}

// ==== src refine — per-bucket histogram -> deg_src (no CSR needed) =======
__global__ __launch_bounds__(256) void k_refine_s(const unsigned* __restrict__ sc_s,
                                                  const unsigned char* __restrict__ recs_s,
                                                  int* __restrict__ deg_src,
                                                  int E, int NB, int N2) {
  __shared__ unsigned hist[256];
  int b = blockIdx.x, t = threadIdx.x;
  int lo = (int)sc_s[(size_t)b * NBLK];
  int hi = (b + 1 < NB) ? (int)sc_s[(size_t)(b + 1) * NBLK] : 2 * E;
  hist[t] = 0;
  __syncthreads();
  for (int j = lo + t; j < hi; j += 256)
    atomicAdd(&hist[recs_s[j]], 1u);
  __syncthreads();
  int node = b * 256 + t;
  if (node < N2) deg_src[node] = (int)hist[t];
}

// ---- xw = x16 @ W via MFMA f16 16x16x32, inv_s fused, fp16 out ----------
__global__ __launch_bounds__(256) void k_gemm(const __half* __restrict__ x16,
                                              const __half* __restrict__ Wt,
                                              const int* __restrict__ deg_src,
                                              __half* __restrict__ xw, int N) {
  __shared__ __half Ws[KC * KC];        // 32 KB: Wt[n][k]
  __shared__ __half outs[64 * 136];     // 17 KB staging (pad 8 halves/row)
  int rel = (blockIdx.x * 64) >= N;
  int t = threadIdx.x;
  const uint4* wg = (const uint4*)(Wt + (size_t)rel * KC * KC);
#pragma unroll
  for (int i = 0; i < 8; ++i)
    ((uint4*)Ws)[t + 256 * i] = wg[t + 256 * i];
  __syncthreads();
  int wid = t >> 6, lane = t & 63;
  int l15 = lane & 15, quad = lane >> 4;
  int row0 = blockIdx.x * 64 + wid * 16;
  half8 a[4];
  const __half* xrow = x16 + (size_t)(row0 + l15) * KC + quad * 8;
#pragma unroll
  for (int ks = 0; ks < 4; ++ks) a[ks] = *(const half8*)(xrow + ks * 32);
  float4v acc[8];
#pragma unroll
  for (int nt = 0; nt < 8; ++nt) {
    acc[nt] = (float4v){0.f, 0.f, 0.f, 0.f};
#pragma unroll
    for (int ks = 0; ks < 4; ++ks) {
      half8 b = *(const half8*)&Ws[(nt * 16 + l15) * KC + ks * 32 + quad * 8];
      acc[nt] = __builtin_amdgcn_mfma_f32_16x16x32_f16(a[ks], b, acc[nt], 0, 0, 0);
    }
  }
  float scv[4];
#pragma unroll
  for (int r = 0; r < 4; ++r) {
    int dg = deg_src[row0 + quad * 4 + r];
    scv[r] = dg > 0 ? rsqrtf((float)dg) : 0.f;
  }
  __half* ob = outs + (size_t)wid * 16 * 136;
#pragma unroll
  for (int nt = 0; nt < 8; ++nt)
#pragma unroll
    for (int r = 0; r < 4; ++r)
      ob[(quad * 4 + r) * 136 + nt * 16 + l15] = __float2half_rn(acc[nt][r] * scv[r]);
  __syncthreads();
  size_t gbase = (size_t)blockIdx.x * 64 * KC;
#pragma unroll
  for (int i = 0; i < 4; ++i) {
    int idx = t + 256 * i;
    int rr = idx >> 4, cc = idx & 15;
    *(uint4*)(xw + gbase + (size_t)rr * KC + cc * 8) =
        *(const uint4*)(outs + (size_t)rr * 136 + cc * 8);
  }
}

// ---- aggregation: fp16 gather, fp32 accumulate, fp16 h out --------------
__global__ void k_agg(const __half* __restrict__ xw, const int* __restrict__ ssrc,
                      const int* __restrict__ endp, const int* __restrict__ deg_dst,
                      __half* __restrict__ h, int n2) {
  int gw = (int)((blockIdx.x * blockDim.x + threadIdx.x) >> 6);
  if (gw >= n2) return;
  int lane = threadIdx.x & 63;
  int half = lane >> 5, l32 = lane & 31;
  int d = deg_dst[gw];
  int end = endp[gw], start = end - d;
  float4 a0 = make_float4(0, 0, 0, 0), a1 = a0;
  int i = start + half;
  for (; i + 2 < end; i += 4) {
    int r0 = ssrc[i], r1 = ssrc[i + 2];
    uint2 u0 = ((const uint2*)(xw + (size_t)r0 * KC))[l32];
    uint2 u1 = ((const uint2*)(xw + (size_t)r1 * KC))[l32];
    float2 f00 = __half22float2(*(__half2*)&u0.x);
    float2 f01 = __half22float2(*(__half2*)&u0.y);
    float2 f10 = __half22float2(*(__half2*)&u1.x);
    float2 f11 = __half22float2(*(__half2*)&u1.y);
    a0.x += f00.x; a0.y += f00.y; a0.z += f01.x; a0.w += f01.y;
    a1.x += f10.x; a1.y += f10.y; a1.z += f11.x; a1.w += f11.y;
  }
  if (i < end) {
    int r = ssrc[i];
    uint2 u = ((const uint2*)(xw + (size_t)r * KC))[l32];
    float2 f0 = __half22float2(*(__half2*)&u.x);
    float2 f1 = __half22float2(*(__half2*)&u.y);
    a0.x += f0.x; a0.y += f0.y; a0.z += f1.x; a0.w += f1.y;
  }
  a0.x += a1.x; a0.y += a1.y; a0.z += a1.z; a0.w += a1.w;
  a0.x += __shfl_xor(a0.x, 32, 64);
  a0.y += __shfl_xor(a0.y, 32, 64);
  a0.z += __shfl_xor(a0.z, 32, 64);
  a0.w += __shfl_xor(a0.w, 32, 64);
  if (half == 0) {
    float invd = d > 0 ? rsqrtf((float)d) : 0.f;
    a0.x = fmaxf(a0.x * invd, 0.f);
    a0.y = fmaxf(a0.y * invd, 0.f);
    a0.z = fmaxf(a0.z * invd, 0.f);
    a0.w = fmaxf(a0.w * invd, 0.f);
    __half2 p0 = __floats2half2_rn(a0.x, a0.y);
    __half2 p1 = __floats2half2_rn(a0.z, a0.w);
    uint2 u; u.x = *(unsigned*)&p0; u.y = *(unsigned*)&p1;
    ((uint2*)(h + (size_t)gw * KC))[l32] = u;
  }
}

// ---- link scorer: half-wave per link, fp16 h gather ---------------------
__global__ void k_links(const __half* __restrict__ h,
                        const int* __restrict__ srcs, const int* __restrict__ dsts,
                        const float* __restrict__ Wp, const float* __restrict__ bp,
                        float* __restrict__ out, int L, int N) {
  int gw = (int)((blockIdx.x * blockDim.x + threadIdx.x) >> 6);
  int lane = threadIdx.x & 63;
  int half = lane >> 5, l32 = lane & 31;
  int li = gw * 2 + half;
  if (li >= L) return;
  int s = srcs[li], dd = dsts[li];
  const __half* hu = h + (size_t)N * KC;
  uint2 ua = ((const uint2*)(hu + (size_t)s * KC))[l32];
  uint2 ub = ((const uint2*)(h + (size_t)dd * KC))[l32];
  float2 a01 = __half22float2(*(__half2*)&ua.x);
  float2 a23 = __half22float2(*(__half2*)&ua.y);
  float2 b01 = __half22float2(*(__half2*)&ub.x);
  float2 b23 = __half22float2(*(__half2*)&ub.y);
  float4 w01 = ((const float4*)Wp)[l32 * 2];
  float4 w23 = ((const float4*)Wp)[l32 * 2 + 1];
  float acc = a01.x * b01.x * (w01.x + w01.y) + a01.y * b01.y * (w01.z + w01.w)
            + a23.x * b23.x * (w23.x + w23.y) + a23.y * b23.y * (w23.z + w23.w);
#pragma unroll
  for (int off = 16; off; off >>= 1) acc += __shfl_down(acc, off, 32);
  if (l32 == 0) out[li] = acc + bp[0] + bp[1];
}

// ========================================================================
extern "C" void kernel_launch(void* const* d_in, const int* in_sizes, int n_in,
                              void* d_out, int out_size, void* d_ws, size_t ws_size,
                              hipStream_t stream) {
  const float* x_user = (const float*)d_in[0];
  const float* x_item = (const float*)d_in[1];
  const int*   edge_ui = (const int*)d_in[2];
  const int*   edge_iu = (const int*)d_in[3];
  const int*   elab    = (const int*)d_in[4];
  const float* p_ui   = (const float*)d_in[5];
  const float* W0_ui  = (const float*)d_in[6];
  const float* Wih_ui = (const float*)d_in[7];
  const float* Whh_ui = (const float*)d_in[8];
  const float* bih_ui = (const float*)d_in[9];
  const float* bhh_ui = (const float*)d_in[10];
  const float* p_iu   = (const float*)d_in[11];
  const float* W0_iu  = (const float*)d_in[12];
  const float* Wih_iu = (const float*)d_in[13];
  const float* Whh_iu = (const float*)d_in[14];
  const float* bih_iu = (const float*)d_in[15];
  const float* bhh_iu = (const float*)d_in[16];
  const float* W_post = (const float*)d_in[17];
  const float* b_post = (const float*)d_in[18];
  const int N = in_sizes[0] / KC;
  const int E = in_sizes[2] / 2;
  const int L = in_sizes[4] / 2;
  const int N2 = 2 * N;
  const int NB = (N2 + 255) >> 8;               // 625 dst/src buckets
  const int chunk = (2 * E + NBLK - 1) / NBLK;  // 7813
  const int NTOT = NB * NBLK;                   // per-segment scan length
  const int SCB = (NTOT + 1023) / 1024;         // scan blocks per segment

  char* wsp = (char*)d_ws;
  auto carve = [&](size_t bytes) -> void* {
    void* p = (void*)wsp;
    wsp += (bytes + 255) & ~(size_t)255;
    return p;
  };
  // zeroed region: hist[2*65536] | ctrl[16 u32]
  const size_t histB = 2 * 65536 * 4;
  const size_t zBytes = histB + 256;
  char*     zbase    = (char*)carve(zBytes);
  unsigned* hist     = (unsigned*)zbase;
  unsigned* ctrl     = (unsigned*)(zbase + histB);
  // non-zeroed scratch
  int*      deg_src  = (int*)carve((size_t)N2 * 4);
  __half*   x16      = (__half*)carve((size_t)N2 * KC * 2);
  __half*   xw       = (__half*)carve((size_t)N2 * KC * 2);
  __half*   h        = (__half*)carve((size_t)N2 * KC * 2);  // [h_item | h_user]
  float*    scores   = (float*)carve((size_t)N2 * 4);
  int*      cand_idx = (int*)carve(2 * 2048 * 4);
  float*    cand_val = (float*)carve(2 * 2048 * 4);
  int*      top_idx  = (int*)carve(2 * KC * 4);
  float*    top_tanh = (float*)carve(2 * KC * 4);
  float*    Xt       = (float*)carve(2 * KC * KC * 4);
  __half*   Wt16     = (__half*)carve(2 * KC * KC * 2);
  unsigned* cnts     = (unsigned*)carve((size_t)2 * NTOT * 4);  // [dst | src]
  unsigned* sc       = (unsigned*)carve((size_t)2 * NTOT * 4);  // [dst | src]
  unsigned* bsum     = (unsigned*)carve(2 * SCB * 4);
  unsigned* recs     = (unsigned*)carve((size_t)2 * E * 4);
  unsigned char* recs_s = (unsigned char*)carve((size_t)2 * E);
  int*      ssrc     = (int*)carve((size_t)2 * E * 4);
  int*      deg_dst  = (int*)carve((size_t)N2 * 4);
  int*      endp     = (int*)carve((size_t)N2 * 4);

  hipMemsetAsync(zbase, 0, zBytes, stream);

  // fused: dual bucket counts + scores + x16 (no global scattered atomics)
  k_cnt2<<<NBLK, 256, 0, stream>>>(edge_ui, edge_iu, x_user, x_item, p_ui, p_iu,
                                   scores, hist, x16, cnts, E, N, NB, chunk, NTOT);
  // scans over both segments in one chain
  k_scan1<<<2 * SCB, 1024, 0, stream>>>(cnts, sc, bsum, NTOT, NB, SCB);
  k_scan2<<<2, 256, 0, stream>>>(bsum, SCB);
  k_scan3<<<(2 * NTOT + 255) / 256, 256, 0, stream>>>(sc, bsum, NTOT, SCB);
  // partitions + refines
  k_part<<<NBLK, 256, 0, stream>>>(edge_ui, edge_iu, cnts, sc, recs, E, N, NB, chunk);
  k_part_s<<<NBLK, 256, 0, stream>>>(edge_ui, edge_iu, cnts + NTOT, sc + NTOT, recs_s,
                                     E, N, NB, chunk);
  k_refine<<<NB, 256, 0, stream>>>(sc, recs, ssrc, deg_dst, endp, E, NB, N2);
  k_refine_s<<<NB, 256, 0, stream>>>(sc + NTOT, recs_s, deg_src, E, NB, N2);

  // TopK pooling + GRU
  k_thresh<<<2, 1024, 0, stream>>>(hist, ctrl);
  k_compact<<<(N2 + 255) / 256, 256, 0, stream>>>(scores, ctrl, cand_idx, cand_val, N);
  k_topk<<<2, 128, 0, stream>>>(ctrl, cand_idx, cand_val, p_ui, p_iu, top_idx, top_tanh);
  k_xtilde<<<2 * KC * KC / 256, 256, 0, stream>>>(x_user, x_item, top_idx, top_tanh, Xt);
  k_gru<<<2 * KC, KC, 0, stream>>>(Xt, W0_ui, W0_iu, Wih_ui, Wih_iu, Whh_ui, Whh_iu,
                                   bih_ui, bih_iu, bhh_ui, bhh_iu, Wt16);

  // GCN: MFMA gemm (inv_s fused, fp16 out) then gather-aggregate
  k_gemm<<<N2 / 64, 256, 0, stream>>>(x16, Wt16, deg_src, xw, N);
  k_agg<<<(N2 + 3) / 4, 256, 0, stream>>>(xw, ssrc, endp, deg_dst, h, N2);
  // Link scorer
  k_links<<<((L + 1) / 2 + 3) / 4, 256, 0, stream>>>(h, elab, elab + L, W_post, b_post,
                                                     (float*)d_out, L, N);
}

// Round 8
// 485.603 us; speedup vs baseline: 1.1376x; 1.1376x over previous
//
#include <hip/hip_runtime.h>
#include <hip/hip_fp16.h>

constexpr int KC   = 128;    // channels
constexpr int NBLK = 2048;   // partition/count blocks (8/CU)
constexpr int CAPA = 1024;   // per-block edge chunk cap (chunk = 2M/2048 = 977)
constexpr int CAPB = 4608;   // per-bucket edge cap (mean 3200, sd 57 -> +24 sigma)

using half8  = __attribute__((ext_vector_type(8))) _Float16;
using float4v = __attribute__((ext_vector_type(4))) float;

// ---------------------------------------------------------------- helpers
__device__ __forceinline__ unsigned fkey(float s) {
  unsigned u = __float_as_uint(s);
  return (u & 0x80000000u) ? ~u : (u | 0x80000000u);
}

// block-wide in-place exclusive scan of arr[0..M), 256 threads, M<=1024
__device__ __forceinline__ void block_exscan(unsigned* arr, int M, unsigned* tmp4) {
  int t = threadIdx.x;
  const int K = (M + 255) >> 8;
  unsigned loc[4];
  unsigned s = 0;
  int base = t * K;
#pragma unroll
  for (int k = 0; k < 4; ++k) {
    if (k < K) {
      unsigned v = (base + k < M) ? arr[base + k] : 0;
      loc[k] = s; s += v;
    }
  }
  unsigned inc = s;
#pragma unroll
  for (int off = 1; off < 64; off <<= 1) {
    unsigned u = __shfl_up(inc, off, 64);
    if ((t & 63) >= off) inc += u;
  }
  int w = t >> 6;
  if ((t & 63) == 63) tmp4[w] = inc;
  __syncthreads();
  unsigned wbase = 0;
  if (w > 0) wbase += tmp4[0];
  if (w > 1) wbase += tmp4[1];
  if (w > 2) wbase += tmp4[2];
  unsigned exc = wbase + inc - s;
  __syncthreads();
#pragma unroll
  for (int k = 0; k < 4; ++k)
    if (k < K && base + k < M) arr[base + k] = exc + loc[k];
  __syncthreads();
}

// ---- scores + histogram + fp16 copy of x: one wave per row (40K blocks) --
__global__ void k_scores(const float* __restrict__ xu, const float* __restrict__ xi,
                         const float* __restrict__ pu, const float* __restrict__ pi,
                         float* __restrict__ scores, unsigned* __restrict__ hist,
                         __half* __restrict__ x16, int N) {
  int gw = (int)((blockIdx.x * blockDim.x + threadIdx.x) >> 6);
  int lane = threadIdx.x & 63;
  if (gw >= 2 * N) return;
  int rel = gw >= N;
  int r = gw - rel * N;
  const float* x = rel ? xi : xu;
  const float* p = rel ? pi : pu;
  float2 xv = ((const float2*)(x + (size_t)r * KC))[lane];
  float2 pv = ((const float2*)p)[lane];
  *(__half2*)(x16 + (size_t)gw * KC + lane * 2) = __floats2half2_rn(xv.x, xv.y);
  float s = xv.x * pv.x + xv.y * pv.y;
#pragma unroll
  for (int off = 32; off; off >>= 1) s += __shfl_down(s, off, 64);
  if (lane == 0) {
    scores[gw] = s;
    atomicAdd(&hist[rel * 65536 + (fkey(s) >> 16)], 1u);
  }
}

// ==== dual bucket counts (src+dst), LDS only, 2048 blocks ================
__global__ __launch_bounds__(256) void k_cnt(const int* __restrict__ eui,
                                             const int* __restrict__ eiu,
                                             unsigned* __restrict__ cnts,
                                             int E, int N, int NB, int chunk, int NTOT) {
  __shared__ unsigned hD[640], hS[640];
  int t = threadIdx.x, blk = blockIdx.x;
  for (int b = t; b < NB; b += 256) { hD[b] = 0; hS[b] = 0; }
  __syncthreads();
  int lo = blk * chunk, hi = min(2 * E, lo + chunk);
  for (int i = lo + t; i < hi; i += 256) {
    int rel = i >= E;
    const int* e = rel ? eiu : eui;
    int j = i - rel * E;
    atomicAdd(&hD[(rel * N + e[E + j]) >> 8], 1u);
    atomicAdd(&hS[(rel * N + e[j]) >> 8], 1u);
  }
  __syncthreads();
  for (int b = t; b < NB; b += 256) {
    cnts[(size_t)blk * NB + b] = hD[b];
    cnts[(size_t)NTOT + (size_t)blk * NB + b] = hS[b];
  }
}

// ---- threshold bin (blockIdx = relation) --------------------------------
__global__ void k_thresh(const unsigned* __restrict__ hist, unsigned* __restrict__ ctrl) {
  const unsigned* h = hist + blockIdx.x * 65536;
  unsigned* c = ctrl + blockIdx.x * 8;
  __shared__ unsigned csum[1024];
  __shared__ int s_chunk;
  __shared__ unsigned s_above;
  int t = threadIdx.x;
  unsigned s = 0;
  int hi = 65536 - 64 * t;
  for (int b = hi - 64; b < hi; ++b) s += h[b];
  csum[t] = s;
  __syncthreads();
  for (int off = 1; off < 1024; off <<= 1) {
    unsigned add = (t >= off) ? csum[t - off] : 0;
    __syncthreads();
    csum[t] += add;
    __syncthreads();
  }
  unsigned above = (t == 0) ? 0u : csum[t - 1];
  if (csum[t] >= 128u && above < 128u) { s_chunk = t; s_above = above; }
  __syncthreads();
  int chi = 65536 - 64 * s_chunk;
  __shared__ unsigned bs[64];
  if (t < 64) bs[t] = h[chi - 1 - t];
  __syncthreads();
  if (t < 64) {
    unsigned v = bs[t], cum = v;
#pragma unroll
    for (int off = 1; off < 64; off <<= 1) {
      unsigned u = __shfl_up(cum, off, 64);
      if (t >= off) cum += u;
    }
    unsigned prev = cum - v;
    if (s_above + cum >= 128u && s_above + prev < 128u)
      c[0] = (unsigned)(chi - 1 - t);
  }
}

// ---- compact candidates -------------------------------------------------
__global__ void k_compact(const float* __restrict__ scores, unsigned* __restrict__ ctrl,
                          int* __restrict__ cand_idx, float* __restrict__ cand_val, int N) {
  int i = blockIdx.x * blockDim.x + threadIdx.x;
  if (i >= 2 * N) return;
  int rel = i >= N;
  float s = scores[i];
  if ((fkey(s) >> 16) >= ctrl[rel * 8]) {
    unsigned pos = atomicAdd(&ctrl[rel * 8 + 1], 1u);
    if (pos < 2048u) {
      cand_idx[rel * 2048 + pos] = i - rel * N;
      cand_val[rel * 2048 + pos] = s;
    }
  }
}

// ---- exact rank among candidates ---------------------------------------
__global__ void k_topk(const unsigned* __restrict__ ctrl,
                       const int* __restrict__ cand_idx, const float* __restrict__ cand_val,
                       const float* __restrict__ pu, const float* __restrict__ pi,
                       int* __restrict__ top_idx, float* __restrict__ top_tanh) {
  __shared__ float vals[2048];
  __shared__ int   idxs[2048];
  __shared__ float red[128];
  int rel = blockIdx.x, t = threadIdx.x;
  const float* p = rel ? pi : pu;
  int n = (int)ctrl[rel * 8 + 1]; if (n > 2048) n = 2048;
  for (int i = t; i < n; i += 128) {
    vals[i] = cand_val[rel * 2048 + i];
    idxs[i] = cand_idx[rel * 2048 + i];
  }
  float pv = p[t];
  red[t] = pv * pv;
  __syncthreads();
  for (int off = 64; off; off >>= 1) { if (t < off) red[t] += red[t + off]; __syncthreads(); }
  float pn = sqrtf(red[0]) + 1e-16f;
  for (int c = t; c < n; c += 128) {
    float v = vals[c]; int id = idxs[c];
    int rank = 0;
    for (int j = 0; j < n; ++j) {
      float vj = vals[j];
      rank += (vj > v) || (vj == v && idxs[j] < id);
    }
    if (rank < KC) {
      top_idx[rel * KC + rank] = id;
      top_tanh[rel * KC + rank] = tanhf(v / pn);
    }
  }
}

// ---- X_tilde ------------------------------------------------------------
__global__ void k_xtilde(const float* __restrict__ xu, const float* __restrict__ xi,
                         const int* __restrict__ top_idx, const float* __restrict__ top_tanh,
                         float* __restrict__ Xt) {
  int t = blockIdx.x * blockDim.x + threadIdx.x;
  int rel = t >> 14;
  int c = (t >> 7) & 127, j = t & 127;
  const float* x = rel ? xi : xu;
  Xt[t] = x[(size_t)top_idx[rel * KC + c] * KC + j] * top_tanh[rel * KC + c];
}

// ---- GRU step -> evolved weight, stored fp16 TRANSPOSED -----------------
__global__ void k_gru(const float* __restrict__ Xt,
                      const float* __restrict__ W0u, const float* __restrict__ W0i,
                      const float* __restrict__ Wihu, const float* __restrict__ Wihi,
                      const float* __restrict__ Whhu, const float* __restrict__ Whhi,
                      const float* __restrict__ bihu, const float* __restrict__ bihi,
                      const float* __restrict__ bhhu, const float* __restrict__ bhhi,
                      __half* __restrict__ Wt) {
  __shared__ float xt[KC], w0[KC];
  int rel = blockIdx.x >> 7, c = blockIdx.x & 127, k = threadIdx.x;
  const float* W0  = rel ? W0i  : W0u;
  const float* Wih = rel ? Wihi : Wihu;
  const float* Whh = rel ? Whhi : Whhu;
  const float* bih = rel ? bihi : bihu;
  const float* bhh = rel ? bhhi : bhhu;
  xt[k] = Xt[rel * KC * KC + c * KC + k];
  w0[k] = W0[c * KC + k];
  __syncthreads();
  float gir = bih[k], giz = bih[KC + k], gin = bih[2 * KC + k];
  float ghr = bhh[k], ghz = bhh[KC + k], ghn = bhh[2 * KC + k];
  const float* wr = Wih + (size_t)k * KC;
  const float* wz = Wih + (size_t)(KC + k) * KC;
  const float* wn = Wih + (size_t)(2 * KC + k) * KC;
  const float* vr = Whh + (size_t)k * KC;
  const float* vz = Whh + (size_t)(KC + k) * KC;
  const float* vn = Whh + (size_t)(2 * KC + k) * KC;
  for (int j = 0; j < KC; ++j) {
    float xj = xt[j], hj = w0[j];
    gir += xj * wr[j]; giz += xj * wz[j]; gin += xj * wn[j];
    ghr += hj * vr[j]; ghz += hj * vz[j]; ghn += hj * vn[j];
  }
  float r = 1.f / (1.f + expf(-(gir + ghr)));
  float z = 1.f / (1.f + expf(-(giz + ghz)));
  float nn = tanhf(gin + r * ghn);
  float w = (1.f - z) * nn + z * w0[k];
  Wt[(size_t)rel * KC * KC + (size_t)k * KC + c] = __float2half_rn(w);
}

// ==== scan: two segments (dst | src), bucket-major reorder on read =======
__global__ void k_scan1(const unsigned* __restrict__ cnts, unsigned* __restrict__ sc,
                        unsigned* __restrict__ bsum, int NTOT, int NB, int SCB) {
  __shared__ unsigned sh[1024];
  int t = threadIdx.x;
  int seg = blockIdx.x / SCB, lb = blockIdx.x % SCB;
  int li = lb * 1024 + t;
  unsigned v = 0;
  if (li < NTOT) {
    int b = li >> 11, blk = li & (NBLK - 1);       // li = b*NBLK + blk
    v = cnts[(size_t)seg * NTOT + (size_t)blk * NB + b];
  }
  sh[t] = v; __syncthreads();
  for (int off = 1; off < 1024; off <<= 1) {
    unsigned add = (t >= off) ? sh[t - off] : 0;
    __syncthreads();
    sh[t] += add;
    __syncthreads();
  }
  if (li < NTOT) sc[(size_t)seg * NTOT + li] = sh[t] - v;
  if (t == 1023) bsum[blockIdx.x] = sh[1023];
}

// K=8 block scan over up to 2048 block-sums, one block per segment
__global__ void k_scan2(unsigned* __restrict__ bsum, int nb) {
  __shared__ unsigned sh[2048];
  __shared__ unsigned tmp4[4];
  unsigned* bs = bsum + blockIdx.x * nb;
  int t = threadIdx.x;
  for (int i = t; i < 2048; i += 256) sh[i] = (i < nb) ? bs[i] : 0;
  __syncthreads();
  unsigned loc[8]; unsigned s = 0;
  int base = t * 8;
#pragma unroll
  for (int k = 0; k < 8; ++k) { unsigned v = sh[base + k]; loc[k] = s; s += v; }
  unsigned inc = s;
#pragma unroll
  for (int off = 1; off < 64; off <<= 1) {
    unsigned u = __shfl_up(inc, off, 64);
    if ((t & 63) >= off) inc += u;
  }
  int w = t >> 6;
  if ((t & 63) == 63) tmp4[w] = inc;
  __syncthreads();
  unsigned wbase = 0;
  if (w > 0) wbase += tmp4[0];
  if (w > 1) wbase += tmp4[1];
  if (w > 2) wbase += tmp4[2];
  unsigned exc = wbase + inc - s;
  __syncthreads();
#pragma unroll
  for (int k = 0; k < 8; ++k) sh[base + k] = exc + loc[k];
  __syncthreads();
  for (int i = t; i < nb; i += 256) bs[i] = sh[i];
}

__global__ void k_scan3(unsigned* __restrict__ sc, const unsigned* __restrict__ bsum,
                        int NTOT, int SCB) {
  int i = blockIdx.x * blockDim.x + threadIdx.x;
  if (i >= 2 * NTOT) return;
  int seg = i >= NTOT;
  int li = i - seg * NTOT;
  sc[i] += bsum[seg * SCB + (li >> 10)];
}

// ==== dst partition — block-local counting sort, coalesced write =========
__global__ __launch_bounds__(256) void k_part(const int* __restrict__ eui,
                                              const int* __restrict__ eiu,
                                              const unsigned* __restrict__ cnts,
                                              const unsigned* __restrict__ sc,
                                              unsigned* __restrict__ recs,
                                              int E, int N, int NB, int chunk) {
  __shared__ unsigned hist[640];
  __shared__ unsigned cur[640];
  __shared__ unsigned delta[640];
  __shared__ unsigned tmp4[4];
  __shared__ unsigned stage[CAPA];
  __shared__ unsigned short bkt16[CAPA];
  int t = threadIdx.x, blk = blockIdx.x;
  for (int b = t; b < NB; b += 256) hist[b] = cnts[(size_t)blk * NB + b];
  __syncthreads();
  int lo = blk * chunk, hi = min(2 * E, lo + chunk);
  block_exscan(hist, NB, tmp4);
  for (int b = t; b < NB; b += 256) cur[b] = hist[b];
  __syncthreads();
  for (int i = lo + t; i < hi; i += 256) {
    int rel = i >= E;
    const int* e = rel ? eiu : eui;
    int j = i - rel * E;
    int src_g = rel * N + e[j];
    int dst_g = rel * N + e[E + j];
    int b = dst_g >> 8;
    unsigned pos = atomicAdd(&cur[b], 1u);
    stage[pos] = (unsigned)src_g | ((unsigned)(dst_g & 255) << 18);
    bkt16[pos] = (unsigned short)b;
  }
  for (int b = t; b < NB; b += 256)
    delta[b] = sc[(size_t)b * NBLK + blk] - hist[b];
  __syncthreads();
  int cnt = hi - lo;
  for (int j = t; j < cnt; j += 256)
    recs[delta[bkt16[j]] + j] = stage[j];
}

// ==== src partition — byte records ======================================
__global__ __launch_bounds__(256) void k_part_s(const int* __restrict__ eui,
                                                const int* __restrict__ eiu,
                                                const unsigned* __restrict__ cnts_s,
                                                const unsigned* __restrict__ sc_s,
                                                unsigned char* __restrict__ recs_s,
                                                int E, int N, int NB, int chunk) {
  __shared__ unsigned hist[640];
  __shared__ unsigned cur[640];
  __shared__ unsigned delta[640];
  __shared__ unsigned tmp4[4];
  __shared__ unsigned char stageB[CAPA];
  __shared__ unsigned short bkt16[CAPA];
  int t = threadIdx.x, blk = blockIdx.x;
  for (int b = t; b < NB; b += 256) hist[b] = cnts_s[(size_t)blk * NB + b];
  __syncthreads();
  int lo = blk * chunk, hi = min(2 * E, lo + chunk);
  block_exscan(hist, NB, tmp4);
  for (int b = t; b < NB; b += 256) cur[b] = hist[b];
  __syncthreads();
  for (int i = lo + t; i < hi; i += 256) {
    int rel = i >= E;
    const int* e = rel ? eiu : eui;
    int j = i - rel * E;
    int src_g = rel * N + e[j];
    int b = src_g >> 8;
    unsigned pos = atomicAdd(&cur[b], 1u);
    stageB[pos] = (unsigned char)(src_g & 255);
    bkt16[pos] = (unsigned short)b;
  }
  for (int b = t; b < NB; b += 256)
    delta[b] = sc_s[(size_t)b * NBLK + blk] - hist[b];
  __syncthreads();
  int cnt = hi - lo;
  for (int j = t; j < cnt; j += 256)
    recs_s[delta[bkt16[j]] + j] = stageB[j];
}

// ==== dst refine — per-bucket exact CSR + deg_dst/endp ===================
__global__ __launch_bounds__(256) void k_refine(const unsigned* __restrict__ sc,
                                                const unsigned* __restrict__ recs,
                                                int* __restrict__ ssrc,
                                                int* __restrict__ deg_dst,
                                                int* __restrict__ endp,
                                                int E, int NB, int N2) {
  __shared__ unsigned hist[256];
  __shared__ unsigned cur[256];
  __shared__ unsigned tmp4[4];
  __shared__ unsigned stage[CAPB];
  int b = blockIdx.x, t = threadIdx.x;
  int lo = (int)sc[(size_t)b * NBLK];
  int hi = (b + 1 < NB) ? (int)sc[(size_t)(b + 1) * NBLK] : 2 * E;
  int cnt = hi - lo; if (cnt > CAPB) cnt = CAPB;
  hist[t] = 0;
  __syncthreads();
  for (int j = t; j < cnt; j += 256)
    atomicAdd(&hist[recs[lo + j] >> 18], 1u);
  __syncthreads();
  unsigned h0 = hist[t];
  block_exscan(hist, 256, tmp4);
  int dst_g = b * 256 + t;
  if (dst_g < N2) {
    deg_dst[dst_g] = (int)h0;
    endp[dst_g] = lo + (int)(hist[t] + h0);
  }
  cur[t] = hist[t];
  __syncthreads();
  for (int j = t; j < cnt; j += 256) {
    unsigned rec = recs[lo + j];
    unsigned pos = atomicAdd(&cur[rec >> 18], 1u);
    stage[pos] = rec & 0x3FFFFu;
  }
  __syncthreads();
  for (int j = t; j < cnt; j += 256)
    ssrc[lo + j] = (int)stage[j];
}

// ==== src refine — per-bucket histogram -> deg_src =======================
__global__ __launch_bounds__(256) void k_refine_s(const unsigned* __restrict__ sc_s,
                                                  const unsigned char* __restrict__ recs_s,
                                                  int* __restrict__ deg_src,
                                                  int E, int NB, int N2) {
  __shared__ unsigned hist[256];
  int b = blockIdx.x, t = threadIdx.x;
  int lo = (int)sc_s[(size_t)b * NBLK];
  int hi = (b + 1 < NB) ? (int)sc_s[(size_t)(b + 1) * NBLK] : 2 * E;
  hist[t] = 0;
  __syncthreads();
  for (int j = lo + t; j < hi; j += 256)
    atomicAdd(&hist[recs_s[j]], 1u);
  __syncthreads();
  int node = b * 256 + t;
  if (node < N2) deg_src[node] = (int)hist[t];
}

// ---- xw = x16 @ W via MFMA f16 16x16x32, inv_s fused, fp16 out ----------
__global__ __launch_bounds__(256) void k_gemm(const __half* __restrict__ x16,
                                              const __half* __restrict__ Wt,
                                              const int* __restrict__ deg_src,
                                              __half* __restrict__ xw, int N) {
  __shared__ __half Ws[KC * KC];        // 32 KB: Wt[n][k]
  __shared__ __half outs[64 * 136];     // 17 KB staging (pad 8 halves/row)
  int rel = (blockIdx.x * 64) >= N;
  int t = threadIdx.x;
  const uint4* wg = (const uint4*)(Wt + (size_t)rel * KC * KC);
#pragma unroll
  for (int i = 0; i < 8; ++i)
    ((uint4*)Ws)[t + 256 * i] = wg[t + 256 * i];
  __syncthreads();
  int wid = t >> 6, lane = t & 63;
  int l15 = lane & 15, quad = lane >> 4;
  int row0 = blockIdx.x * 64 + wid * 16;
  half8 a[4];
  const __half* xrow = x16 + (size_t)(row0 + l15) * KC + quad * 8;
#pragma unroll
  for (int ks = 0; ks < 4; ++ks) a[ks] = *(const half8*)(xrow + ks * 32);
  float4v acc[8];
#pragma unroll
  for (int nt = 0; nt < 8; ++nt) {
    acc[nt] = (float4v){0.f, 0.f, 0.f, 0.f};
#pragma unroll
    for (int ks = 0; ks < 4; ++ks) {
      half8 b = *(const half8*)&Ws[(nt * 16 + l15) * KC + ks * 32 + quad * 8];
      acc[nt] = __builtin_amdgcn_mfma_f32_16x16x32_f16(a[ks], b, acc[nt], 0, 0, 0);
    }
  }
  float scv[4];
#pragma unroll
  for (int r = 0; r < 4; ++r) {
    int dg = deg_src[row0 + quad * 4 + r];
    scv[r] = dg > 0 ? rsqrtf((float)dg) : 0.f;
  }
  __half* ob = outs + (size_t)wid * 16 * 136;
#pragma unroll
  for (int nt = 0; nt < 8; ++nt)
#pragma unroll
    for (int r = 0; r < 4; ++r)
      ob[(quad * 4 + r) * 136 + nt * 16 + l15] = __float2half_rn(acc[nt][r] * scv[r]);
  __syncthreads();
  size_t gbase = (size_t)blockIdx.x * 64 * KC;
#pragma unroll
  for (int i = 0; i < 4; ++i) {
    int idx = t + 256 * i;
    int rr = idx >> 4, cc = idx & 15;
    *(uint4*)(xw + gbase + (size_t)rr * KC + cc * 8) =
        *(const uint4*)(outs + (size_t)rr * 136 + cc * 8);
  }
}

// ---- aggregation: quarter-wave per edge row (full 256B row per uint4 load)
// 4 quarters x unroll 2 = 8 independent row-gathers in flight per wave.
__global__ void k_agg(const __half* __restrict__ xw, const int* __restrict__ ssrc,
                      const int* __restrict__ endp, const int* __restrict__ deg_dst,
                      __half* __restrict__ h, int n2) {
  int gw = (int)((blockIdx.x * blockDim.x + threadIdx.x) >> 6);
  if (gw >= n2) return;
  int lane = threadIdx.x & 63;
  int q = lane >> 4, l16 = lane & 15;
  int d = deg_dst[gw];
  int end = endp[gw], start = end - d;
  float a0[8] = {0, 0, 0, 0, 0, 0, 0, 0};
  float a1[8] = {0, 0, 0, 0, 0, 0, 0, 0};
  int i = start + q;
  for (; i + 4 < end; i += 8) {
    int r0 = ssrc[i], r1 = ssrc[i + 4];
    uint4 u0 = ((const uint4*)(xw + (size_t)r0 * KC))[l16];
    uint4 u1 = ((const uint4*)(xw + (size_t)r1 * KC))[l16];
    const __half2* p0 = (const __half2*)&u0;
    const __half2* p1 = (const __half2*)&u1;
#pragma unroll
    for (int k = 0; k < 4; ++k) {
      float2 f0 = __half22float2(p0[k]);
      float2 f1 = __half22float2(p1[k]);
      a0[2 * k] += f0.x; a0[2 * k + 1] += f0.y;
      a1[2 * k] += f1.x; a1[2 * k + 1] += f1.y;
    }
  }
  if (i < end) {
    int r = ssrc[i];
    uint4 u = ((const uint4*)(xw + (size_t)r * KC))[l16];
    const __half2* p = (const __half2*)&u;
#pragma unroll
    for (int k = 0; k < 4; ++k) {
      float2 f = __half22float2(p[k]);
      a0[2 * k] += f.x; a0[2 * k + 1] += f.y;
    }
  }
#pragma unroll
  for (int k = 0; k < 8; ++k) {
    a0[k] += a1[k];
    a0[k] += __shfl_xor(a0[k], 16, 64);
    a0[k] += __shfl_xor(a0[k], 32, 64);
  }
  if (q == 0) {
    float invd = d > 0 ? rsqrtf((float)d) : 0.f;
    __half2 pk[4];
#pragma unroll
    for (int k = 0; k < 4; ++k)
      pk[k] = __floats2half2_rn(fmaxf(a0[2 * k] * invd, 0.f),
                                fmaxf(a0[2 * k + 1] * invd, 0.f));
    uint4 u;
    u.x = *(unsigned*)&pk[0]; u.y = *(unsigned*)&pk[1];
    u.z = *(unsigned*)&pk[2]; u.w = *(unsigned*)&pk[3];
    ((uint4*)(h + (size_t)gw * KC))[l16] = u;
  }
}

// ---- link scorer: quarter-wave per link (4 links/wave, 8 rows in flight) -
__global__ void k_links(const __half* __restrict__ h,
                        const int* __restrict__ srcs, const int* __restrict__ dsts,
                        const float* __restrict__ Wp, const float* __restrict__ bp,
                        float* __restrict__ out, int L, int N) {
  int gw = (int)((blockIdx.x * blockDim.x + threadIdx.x) >> 6);
  int lane = threadIdx.x & 63;
  int q = lane >> 4, l16 = lane & 15;
  int li = gw * 4 + q;
  if (li >= L) return;
  int s = srcs[li], dd = dsts[li];
  const __half* hu = h + (size_t)N * KC;
  uint4 ua = ((const uint4*)(hu + (size_t)s * KC))[l16];
  uint4 ub = ((const uint4*)(h + (size_t)dd * KC))[l16];
  const __half2* pa = (const __half2*)&ua;
  const __half2* pb = (const __half2*)&ub;
  float acc = 0.f;
#pragma unroll
  for (int k = 0; k < 4; ++k) {
    float2 fa = __half22float2(pa[k]);
    float2 fb = __half22float2(pb[k]);
    float4 w = ((const float4*)Wp)[l16 * 4 + k];   // ch 2k,2k+1 of lane's 8
    acc += fa.x * fb.x * (w.x + w.y) + fa.y * fb.y * (w.z + w.w);
  }
#pragma unroll
  for (int off = 8; off; off >>= 1) acc += __shfl_xor(acc, off, 64);
  if (l16 == 0) out[li] = acc + bp[0] + bp[1];
}

// ========================================================================
extern "C" void kernel_launch(void* const* d_in, const int* in_sizes, int n_in,
                              void* d_out, int out_size, void* d_ws, size_t ws_size,
                              hipStream_t stream) {
  const float* x_user = (const float*)d_in[0];
  const float* x_item = (const float*)d_in[1];
  const int*   edge_ui = (const int*)d_in[2];
  const int*   edge_iu = (const int*)d_in[3];
  const int*   elab    = (const int*)d_in[4];
  const float* p_ui   = (const float*)d_in[5];
  const float* W0_ui  = (const float*)d_in[6];
  const float* Wih_ui = (const float*)d_in[7];
  const float* Whh_ui = (const float*)d_in[8];
  const float* bih_ui = (const float*)d_in[9];
  const float* bhh_ui = (const float*)d_in[10];
  const float* p_iu   = (const float*)d_in[11];
  const float* W0_iu  = (const float*)d_in[12];
  const float* Wih_iu = (const float*)d_in[13];
  const float* Whh_iu = (const float*)d_in[14];
  const float* bih_iu = (const float*)d_in[15];
  const float* bhh_iu = (const float*)d_in[16];
  const float* W_post = (const float*)d_in[17];
  const float* b_post = (const float*)d_in[18];
  const int N = in_sizes[0] / KC;
  const int E = in_sizes[2] / 2;
  const int L = in_sizes[4] / 2;
  const int N2 = 2 * N;
  const int NB = (N2 + 255) >> 8;               // 625 buckets
  const int chunk = (2 * E + NBLK - 1) / NBLK;  // 977
  const int NTOT = NB * NBLK;                   // 1.28M per segment
  const int SCB = (NTOT + 1023) / 1024;         // 1250 scan blocks / segment

  char* wsp = (char*)d_ws;
  auto carve = [&](size_t bytes) -> void* {
    void* p = (void*)wsp;
    wsp += (bytes + 255) & ~(size_t)255;
    return p;
  };
  // zeroed region: hist[2*65536] | ctrl[16 u32]
  const size_t histB = 2 * 65536 * 4;
  const size_t zBytes = histB + 256;
  char*     zbase    = (char*)carve(zBytes);
  unsigned* hist     = (unsigned*)zbase;
  unsigned* ctrl     = (unsigned*)(zbase + histB);
  // non-zeroed scratch
  int*      deg_src  = (int*)carve((size_t)N2 * 4);
  __half*   x16      = (__half*)carve((size_t)N2 * KC * 2);
  __half*   xw       = (__half*)carve((size_t)N2 * KC * 2);
  __half*   h        = (__half*)carve((size_t)N2 * KC * 2);  // [h_item | h_user]
  float*    scores   = (float*)carve((size_t)N2 * 4);
  int*      cand_idx = (int*)carve(2 * 2048 * 4);
  float*    cand_val = (float*)carve(2 * 2048 * 4);
  int*      top_idx  = (int*)carve(2 * KC * 4);
  float*    top_tanh = (float*)carve(2 * KC * 4);
  float*    Xt       = (float*)carve(2 * KC * KC * 4);
  __half*   Wt16     = (__half*)carve(2 * KC * KC * 2);
  unsigned* cnts     = (unsigned*)carve((size_t)2 * NTOT * 4);  // [dst | src]
  unsigned* sc       = (unsigned*)carve((size_t)2 * NTOT * 4);  // [dst | src]
  unsigned* bsum     = (unsigned*)carve((size_t)2 * SCB * 4);
  unsigned* recs     = (unsigned*)carve((size_t)2 * E * 4);
  unsigned char* recs_s = (unsigned char*)carve((size_t)2 * E);
  int*      ssrc     = (int*)carve((size_t)2 * E * 4);
  int*      deg_dst  = (int*)carve((size_t)N2 * 4);
  int*      endp     = (int*)carve((size_t)N2 * 4);

  hipMemsetAsync(zbase, 0, zBytes, stream);

  // scores + x16 (40K blocks, full occupancy)
  k_scores<<<(N2 + 3) / 4, 256, 0, stream>>>(x_user, x_item, p_ui, p_iu, scores, hist,
                                             x16, N);
  // graph sort: dual counts -> scans -> partitions -> refines
  k_cnt<<<NBLK, 256, 0, stream>>>(edge_ui, edge_iu, cnts, E, N, NB, chunk, NTOT);
  k_scan1<<<2 * SCB, 1024, 0, stream>>>(cnts, sc, bsum, NTOT, NB, SCB);
  k_scan2<<<2, 256, 0, stream>>>(bsum, SCB);
  k_scan3<<<(2 * NTOT + 255) / 256, 256, 0, stream>>>(sc, bsum, NTOT, SCB);
  k_part<<<NBLK, 256, 0, stream>>>(edge_ui, edge_iu, cnts, sc, recs, E, N, NB, chunk);
  k_part_s<<<NBLK, 256, 0, stream>>>(edge_ui, edge_iu, cnts + NTOT, sc + NTOT, recs_s,
                                     E, N, NB, chunk);
  k_refine<<<NB, 256, 0, stream>>>(sc, recs, ssrc, deg_dst, endp, E, NB, N2);
  k_refine_s<<<NB, 256, 0, stream>>>(sc + NTOT, recs_s, deg_src, E, NB, N2);

  // TopK pooling + GRU
  k_thresh<<<2, 1024, 0, stream>>>(hist, ctrl);
  k_compact<<<(N2 + 255) / 256, 256, 0, stream>>>(scores, ctrl, cand_idx, cand_val, N);
  k_topk<<<2, 128, 0, stream>>>(ctrl, cand_idx, cand_val, p_ui, p_iu, top_idx, top_tanh);
  k_xtilde<<<2 * KC * KC / 256, 256, 0, stream>>>(x_user, x_item, top_idx, top_tanh, Xt);
  k_gru<<<2 * KC, KC, 0, stream>>>(Xt, W0_ui, W0_iu, Wih_ui, Wih_iu, Whh_ui, Whh_iu,
                                   bih_ui, bih_iu, bhh_ui, bhh_iu, Wt16);

  // GCN: MFMA gemm (inv_s fused, fp16 out) then gather-aggregate
  k_gemm<<<N2 / 64, 256, 0, stream>>>(x16, Wt16, deg_src, xw, N);
  k_agg<<<(N2 + 3) / 4, 256, 0, stream>>>(xw, ssrc, endp, deg_dst, h, N2);
  // Link scorer
  k_links<<<((L + 3) / 4 + 3) / 4, 256, 0, stream>>>(h, elab, elab + L, W_post, b_post,
                                                     (float*)d_out, L, N);
}

// Round 9
// 461.461 us; speedup vs baseline: 1.1971x; 1.0523x over previous
//
#include <hip/hip_runtime.h>
#include <hip/hip_fp16.h>

constexpr int KC    = 128;    // channels
constexpr int NBLK  = 2048;   // count/partition blocks (8/CU)
constexpr int CAPA  = 1024;   // per-block edge chunk cap (chunk = 2M/2048 = 977)
constexpr int CBITS = 12;     // coarse bucket = 4096 nodes
constexpr int CSZ   = 1 << CBITS;

using half8   = __attribute__((ext_vector_type(8))) _Float16;
using float4v = __attribute__((ext_vector_type(4))) float;

// ---------------------------------------------------------------- helpers
__device__ __forceinline__ unsigned fkey(float s) {
  unsigned u = __float_as_uint(s);
  return (u & 0x80000000u) ? ~u : (u | 0x80000000u);
}

// ---- scores + histogram + fp16 copy of x: one wave per row --------------
__global__ void k_scores(const float* __restrict__ xu, const float* __restrict__ xi,
                         const float* __restrict__ pu, const float* __restrict__ pi,
                         float* __restrict__ scores, unsigned* __restrict__ hist,
                         __half* __restrict__ x16, int N) {
  int gw = (int)((blockIdx.x * blockDim.x + threadIdx.x) >> 6);
  int lane = threadIdx.x & 63;
  if (gw >= 2 * N) return;
  int rel = gw >= N;
  int r = gw - rel * N;
  const float* x = rel ? xi : xu;
  const float* p = rel ? pi : pu;
  float2 xv = ((const float2*)(x + (size_t)r * KC))[lane];
  float2 pv = ((const float2*)p)[lane];
  *(__half2*)(x16 + (size_t)gw * KC + lane * 2) = __floats2half2_rn(xv.x, xv.y);
  float s = xv.x * pv.x + xv.y * pv.y;
#pragma unroll
  for (int off = 32; off; off >>= 1) s += __shfl_down(s, off, 64);
  if (lane == 0) {
    scores[gw] = s;
    atomicAdd(&hist[rel * 65536 + (fkey(s) >> 16)], 1u);
  }
}

// ==== coarse bucket counts (src+dst), LDS only, per-wave replicated ======
__global__ __launch_bounds__(256) void k_cnt(const int* __restrict__ eui,
                                             const int* __restrict__ eiu,
                                             unsigned* __restrict__ cnts,
                                             int E, int N, int NBC, int chunk, int NTOT) {
  __shared__ unsigned hD[4 * 48], hS[4 * 48];
  int t = threadIdx.x, blk = blockIdx.x, w = t >> 6;
  for (int b = t; b < 4 * 48; b += 256) { hD[b] = 0; hS[b] = 0; }
  __syncthreads();
  int lo = blk * chunk, hi = min(2 * E, lo + chunk);
  for (int i = lo + t; i < hi; i += 256) {
    int rel = i >= E;
    const int* e = rel ? eiu : eui;
    int j = i - rel * E;
    atomicAdd(&hD[w * 48 + ((rel * N + e[E + j]) >> CBITS)], 1u);
    atomicAdd(&hS[w * 48 + ((rel * N + e[j]) >> CBITS)], 1u);
  }
  __syncthreads();
  for (int b = t; b < NBC; b += 256) {
    cnts[(size_t)blk * NBC + b] = hD[b] + hD[48 + b] + hD[96 + b] + hD[144 + b];
    cnts[(size_t)NTOT + (size_t)blk * NBC + b] =
        hS[b] + hS[48 + b] + hS[96 + b] + hS[144 + b];
  }
}

// ==== scan: two segments (dst | src), bucket-major reorder on read =======
__global__ void k_scan1(const unsigned* __restrict__ cnts, unsigned* __restrict__ sc,
                        unsigned* __restrict__ bsum, int NTOT, int NBC, int SCB) {
  __shared__ unsigned sh[1024];
  int t = threadIdx.x;
  int seg = blockIdx.x / SCB, lb = blockIdx.x % SCB;
  int li = lb * 1024 + t;
  unsigned v = 0;
  if (li < NTOT) {
    int b = li >> 11, blk = li & (NBLK - 1);       // li = b*NBLK + blk
    v = cnts[(size_t)seg * NTOT + (size_t)blk * NBC + b];
  }
  sh[t] = v; __syncthreads();
  for (int off = 1; off < 1024; off <<= 1) {
    unsigned add = (t >= off) ? sh[t - off] : 0;
    __syncthreads();
    sh[t] += add;
    __syncthreads();
  }
  if (li < NTOT) sc[(size_t)seg * NTOT + li] = sh[t] - v;
  if (t == 1023) bsum[blockIdx.x] = sh[1023];
}

__global__ void k_scan2(unsigned* __restrict__ bsum, int nb) {
  __shared__ unsigned sh[256];
  unsigned* bs = bsum + blockIdx.x * nb;
  int t = threadIdx.x;
  unsigned v = (t < nb) ? bs[t] : 0;
  sh[t] = v; __syncthreads();
  for (int off = 1; off < 256; off <<= 1) {
    unsigned add = (t >= off) ? sh[t - off] : 0;
    __syncthreads();
    sh[t] += add;
    __syncthreads();
  }
  if (t < nb) bs[t] = sh[t] - v;
}

// ==== fused dst+src partition — one edge read, coalesced run writes ======
// dst record: src_g(18b) | dst_local12<<18 ; src record: src_local12
__global__ __launch_bounds__(256) void k_part(const int* __restrict__ eui,
                                              const int* __restrict__ eiu,
                                              const unsigned* __restrict__ cnts,
                                              const unsigned* __restrict__ sc,
                                              const unsigned* __restrict__ bsum,
                                              unsigned* __restrict__ recsD,
                                              unsigned* __restrict__ recsS,
                                              int E, int N, int NBC, int chunk,
                                              int NTOT, int SCB) {
  __shared__ unsigned curD[64], curS[64], deltaD[64], deltaS[64];
  __shared__ unsigned stageD[CAPA], stageS[CAPA];
  __shared__ unsigned char bktD[CAPA], bktS[CAPA];
  int t = threadIdx.x, blk = blockIdx.x;
  // exclusive scan of this block's bucket counts (wave0: dst, wave1: src)
  if (t < 64) {
    unsigned v = (t < NBC) ? cnts[(size_t)blk * NBC + t] : 0;
    unsigned cum = v;
#pragma unroll
    for (int off = 1; off < 64; off <<= 1) {
      unsigned u = __shfl_up(cum, off, 64);
      if (t >= off) cum += u;
    }
    if (t < NBC) curD[t] = cum - v;
  } else if (t < 128) {
    int l = t - 64;
    unsigned v = (l < NBC) ? cnts[(size_t)NTOT + (size_t)blk * NBC + l] : 0;
    unsigned cum = v;
#pragma unroll
    for (int off = 1; off < 64; off <<= 1) {
      unsigned u = __shfl_up(cum, off, 64);
      if (l >= off) cum += u;
    }
    if (l < NBC) curS[l] = cum - v;
  }
  __syncthreads();
  if (t < NBC) {
    int li = t * NBLK + blk;
    deltaD[t] = sc[li] + bsum[li >> 10] - curD[t];
    deltaS[t] = sc[NTOT + li] + bsum[SCB + (li >> 10)] - curS[t];
  }
  __syncthreads();
  int lo = blk * chunk, hi = min(2 * E, lo + chunk);
  for (int i = lo + t; i < hi; i += 256) {
    int rel = i >= E;
    const int* e = rel ? eiu : eui;
    int j = i - rel * E;
    int src_g = rel * N + e[j];
    int dst_g = rel * N + e[E + j];
    int bD = dst_g >> CBITS;
    unsigned pD = atomicAdd(&curD[bD], 1u);
    stageD[pD] = (unsigned)src_g | ((unsigned)(dst_g & (CSZ - 1)) << 18);
    bktD[pD] = (unsigned char)bD;
    int bS = src_g >> CBITS;
    unsigned pS = atomicAdd(&curS[bS], 1u);
    stageS[pS] = (unsigned)(src_g & (CSZ - 1));
    bktS[pS] = (unsigned char)bS;
  }
  __syncthreads();
  int cnt = hi - lo;
  for (int j = t; j < cnt; j += 256) {
    recsD[deltaD[bktD[j]] + j] = stageD[j];
    recsS[deltaS[bktS[j]] + j] = stageS[j];
  }
}

// ==== refine: blocks 0..NBC-1 = dst CSR, NBC..2*NBC-1 = src degrees ======
__global__ __launch_bounds__(1024) void k_refine(const unsigned* __restrict__ sc,
                                                 const unsigned* __restrict__ bsum,
                                                 const unsigned* __restrict__ recsD,
                                                 const unsigned* __restrict__ recsS,
                                                 int* __restrict__ ssrc,
                                                 int* __restrict__ deg_dst,
                                                 int* __restrict__ endp,
                                                 int* __restrict__ deg_src,
                                                 int E, int NBC, int N2,
                                                 int NTOT, int SCB) {
  __shared__ unsigned hist[CSZ];
  __shared__ unsigned cur[CSZ];
  __shared__ unsigned tmp16[16];
  int t = threadIdx.x;
  int isS = blockIdx.x >= NBC;
  int c = blockIdx.x - (isS ? NBC : 0);
  size_t soff = isS ? (size_t)NTOT : 0;
  int bso = isS ? SCB : 0;
  int liLo = c * NBLK;
  int lo = (int)(sc[soff + liLo] + bsum[bso + (liLo >> 10)]);
  int hi;
  if (c + 1 < NBC) {
    int liHi = (c + 1) * NBLK;
    hi = (int)(sc[soff + liHi] + bsum[bso + (liHi >> 10)]);
  } else hi = 2 * E;
  for (int b = t; b < CSZ; b += 1024) hist[b] = 0;
  __syncthreads();
  if (isS) {
    for (int j = lo + t; j < hi; j += 1024)
      atomicAdd(&hist[recsS[j]], 1u);
    __syncthreads();
    for (int b = t; b < CSZ; b += 1024) {
      int node = c * CSZ + b;
      if (node < N2) deg_src[node] = (int)hist[b];
    }
  } else {
    for (int j = lo + t; j < hi; j += 1024)
      atomicAdd(&hist[recsD[j] >> 18], 1u);
    __syncthreads();
    // exclusive scan over 4096 entries (4 per thread)
    unsigned loc[4], s = 0;
    int base = t * 4;
#pragma unroll
    for (int k = 0; k < 4; ++k) { unsigned v = hist[base + k]; loc[k] = s; s += v; }
    unsigned inc = s;
#pragma unroll
    for (int off = 1; off < 64; off <<= 1) {
      unsigned u = __shfl_up(inc, off, 64);
      if ((t & 63) >= off) inc += u;
    }
    int w = t >> 6;
    if ((t & 63) == 63) tmp16[w] = inc;
    __syncthreads();
    unsigned wbase = 0;
    for (int j = 0; j < 16; ++j) if (j < w) wbase += tmp16[j];
    unsigned exc = wbase + inc - s;
#pragma unroll
    for (int k = 0; k < 4; ++k) {
      unsigned e0 = exc + loc[k];
      cur[base + k] = e0;
      int node = c * CSZ + base + k;
      if (node < N2) {
        deg_dst[node] = (int)hist[base + k];
        endp[node] = lo + (int)(e0 + hist[base + k]);
      }
    }
    __syncthreads();
    // placement: scatter confined to this bucket's ~200KB segment (L2)
    for (int j = lo + t; j < hi; j += 1024) {
      unsigned rec = recsD[j];
      unsigned pos = atomicAdd(&cur[rec >> 18], 1u);
      ssrc[lo + (int)pos] = (int)(rec & 0x3FFFFu);
    }
  }
}

// ---- threshold bin (blockIdx = relation) --------------------------------
__global__ void k_thresh(const unsigned* __restrict__ hist, unsigned* __restrict__ ctrl) {
  const unsigned* h = hist + blockIdx.x * 65536;
  unsigned* c = ctrl + blockIdx.x * 8;
  __shared__ unsigned csum[1024];
  __shared__ int s_chunk;
  __shared__ unsigned s_above;
  int t = threadIdx.x;
  unsigned s = 0;
  int hi = 65536 - 64 * t;
  for (int b = hi - 64; b < hi; ++b) s += h[b];
  csum[t] = s;
  __syncthreads();
  for (int off = 1; off < 1024; off <<= 1) {
    unsigned add = (t >= off) ? csum[t - off] : 0;
    __syncthreads();
    csum[t] += add;
    __syncthreads();
  }
  unsigned above = (t == 0) ? 0u : csum[t - 1];
  if (csum[t] >= 128u && above < 128u) { s_chunk = t; s_above = above; }
  __syncthreads();
  int chi = 65536 - 64 * s_chunk;
  __shared__ unsigned bs[64];
  if (t < 64) bs[t] = h[chi - 1 - t];
  __syncthreads();
  if (t < 64) {
    unsigned v = bs[t], cum = v;
#pragma unroll
    for (int off = 1; off < 64; off <<= 1) {
      unsigned u = __shfl_up(cum, off, 64);
      if (t >= off) cum += u;
    }
    unsigned prev = cum - v;
    if (s_above + cum >= 128u && s_above + prev < 128u)
      c[0] = (unsigned)(chi - 1 - t);
  }
}

// ---- compact candidates -------------------------------------------------
__global__ void k_compact(const float* __restrict__ scores, unsigned* __restrict__ ctrl,
                          int* __restrict__ cand_idx, float* __restrict__ cand_val, int N) {
  int i = blockIdx.x * blockDim.x + threadIdx.x;
  if (i >= 2 * N) return;
  int rel = i >= N;
  float s = scores[i];
  if ((fkey(s) >> 16) >= ctrl[rel * 8]) {
    unsigned pos = atomicAdd(&ctrl[rel * 8 + 1], 1u);
    if (pos < 2048u) {
      cand_idx[rel * 2048 + pos] = i - rel * N;
      cand_val[rel * 2048 + pos] = s;
    }
  }
}

// ---- exact rank among candidates ---------------------------------------
__global__ void k_topk(const unsigned* __restrict__ ctrl,
                       const int* __restrict__ cand_idx, const float* __restrict__ cand_val,
                       const float* __restrict__ pu, const float* __restrict__ pi,
                       int* __restrict__ top_idx, float* __restrict__ top_tanh) {
  __shared__ float vals[2048];
  __shared__ int   idxs[2048];
  __shared__ float red[128];
  int rel = blockIdx.x, t = threadIdx.x;
  const float* p = rel ? pi : pu;
  int n = (int)ctrl[rel * 8 + 1]; if (n > 2048) n = 2048;
  for (int i = t; i < n; i += 128) {
    vals[i] = cand_val[rel * 2048 + i];
    idxs[i] = cand_idx[rel * 2048 + i];
  }
  float pv = p[t];
  red[t] = pv * pv;
  __syncthreads();
  for (int off = 64; off; off >>= 1) { if (t < off) red[t] += red[t + off]; __syncthreads(); }
  float pn = sqrtf(red[0]) + 1e-16f;
  for (int c = t; c < n; c += 128) {
    float v = vals[c]; int id = idxs[c];
    int rank = 0;
    for (int j = 0; j < n; ++j) {
      float vj = vals[j];
      rank += (vj > v) || (vj == v && idxs[j] < id);
    }
    if (rank < KC) {
      top_idx[rel * KC + rank] = id;
      top_tanh[rel * KC + rank] = tanhf(v / pn);
    }
  }
}

// ---- GRU step (X_tilde fused) -> evolved weight, fp16 TRANSPOSED --------
__global__ void k_gru(const float* __restrict__ xu, const float* __restrict__ xi,
                      const int* __restrict__ top_idx, const float* __restrict__ top_tanh,
                      const float* __restrict__ W0u, const float* __restrict__ W0i,
                      const float* __restrict__ Wihu, const float* __restrict__ Wihi,
                      const float* __restrict__ Whhu, const float* __restrict__ Whhi,
                      const float* __restrict__ bihu, const float* __restrict__ bihi,
                      const float* __restrict__ bhhu, const float* __restrict__ bhhi,
                      __half* __restrict__ Wt) {
  __shared__ float xt[KC], w0[KC];
  int rel = blockIdx.x >> 7, c = blockIdx.x & 127, k = threadIdx.x;
  const float* x   = rel ? xi   : xu;
  const float* W0  = rel ? W0i  : W0u;
  const float* Wih = rel ? Wihi : Wihu;
  const float* Whh = rel ? Whhi : Whhu;
  const float* bih = rel ? bihi : bihu;
  const float* bhh = rel ? bhhi : bhhu;
  xt[k] = x[(size_t)top_idx[rel * KC + c] * KC + k] * top_tanh[rel * KC + c];
  w0[k] = W0[c * KC + k];
  __syncthreads();
  float gir = bih[k], giz = bih[KC + k], gin = bih[2 * KC + k];
  float ghr = bhh[k], ghz = bhh[KC + k], ghn = bhh[2 * KC + k];
  const float* wr = Wih + (size_t)k * KC;
  const float* wz = Wih + (size_t)(KC + k) * KC;
  const float* wn = Wih + (size_t)(2 * KC + k) * KC;
  const float* vr = Whh + (size_t)k * KC;
  const float* vz = Whh + (size_t)(KC + k) * KC;
  const float* vn = Whh + (size_t)(2 * KC + k) * KC;
  for (int j = 0; j < KC; ++j) {
    float xj = xt[j], hj = w0[j];
    gir += xj * wr[j]; giz += xj * wz[j]; gin += xj * wn[j];
    ghr += hj * vr[j]; ghz += hj * vz[j]; ghn += hj * vn[j];
  }
  float r = 1.f / (1.f + expf(-(gir + ghr)));
  float z = 1.f / (1.f + expf(-(giz + ghz)));
  float nn = tanhf(gin + r * ghn);
  float w = (1.f - z) * nn + z * w0[k];
  Wt[(size_t)rel * KC * KC + (size_t)k * KC + c] = __float2half_rn(w);
}

// ---- xw = x16 @ W via MFMA f16 16x16x32, inv_s fused, fp16 out ----------
__global__ __launch_bounds__(256) void k_gemm(const __half* __restrict__ x16,
                                              const __half* __restrict__ Wt,
                                              const int* __restrict__ deg_src,
                                              __half* __restrict__ xw, int N) {
  __shared__ __half Ws[KC * KC];        // 32 KB: Wt[n][k]
  __shared__ __half outs[64 * 136];     // 17 KB staging
  int rel = (blockIdx.x * 64) >= N;
  int t = threadIdx.x;
  const uint4* wg = (const uint4*)(Wt + (size_t)rel * KC * KC);
#pragma unroll
  for (int i = 0; i < 8; ++i)
    ((uint4*)Ws)[t + 256 * i] = wg[t + 256 * i];
  __syncthreads();
  int wid = t >> 6, lane = t & 63;
  int l15 = lane & 15, quad = lane >> 4;
  int row0 = blockIdx.x * 64 + wid * 16;
  half8 a[4];
  const __half* xrow = x16 + (size_t)(row0 + l15) * KC + quad * 8;
#pragma unroll
  for (int ks = 0; ks < 4; ++ks) a[ks] = *(const half8*)(xrow + ks * 32);
  float4v acc[8];
#pragma unroll
  for (int nt = 0; nt < 8; ++nt) {
    acc[nt] = (float4v){0.f, 0.f, 0.f, 0.f};
#pragma unroll
    for (int ks = 0; ks < 4; ++ks) {
      half8 b = *(const half8*)&Ws[(nt * 16 + l15) * KC + ks * 32 + quad * 8];
      acc[nt] = __builtin_amdgcn_mfma_f32_16x16x32_f16(a[ks], b, acc[nt], 0, 0, 0);
    }
  }
  float scv[4];
#pragma unroll
  for (int r = 0; r < 4; ++r) {
    int dg = deg_src[row0 + quad * 4 + r];
    scv[r] = dg > 0 ? rsqrtf((float)dg) : 0.f;
  }
  __half* ob = outs + (size_t)wid * 16 * 136;
#pragma unroll
  for (int nt = 0; nt < 8; ++nt)
#pragma unroll
    for (int r = 0; r < 4; ++r)
      ob[(quad * 4 + r) * 136 + nt * 16 + l15] = __float2half_rn(acc[nt][r] * scv[r]);
  __syncthreads();
  size_t gbase = (size_t)blockIdx.x * 64 * KC;
#pragma unroll
  for (int i = 0; i < 4; ++i) {
    int idx = t + 256 * i;
    int rr = idx >> 4, cc = idx & 15;
    *(uint4*)(xw + gbase + (size_t)rr * KC + cc * 8) =
        *(const uint4*)(outs + (size_t)rr * 136 + cc * 8);
  }
}

// ---- aggregation: quarter-wave, packed fp16 accumulate ------------------
__global__ void k_agg(const __half* __restrict__ xw, const int* __restrict__ ssrc,
                      const int* __restrict__ endp, const int* __restrict__ deg_dst,
                      __half* __restrict__ h, int n2) {
  int gw = (int)((blockIdx.x * blockDim.x + threadIdx.x) >> 6);
  if (gw >= n2) return;
  int lane = threadIdx.x & 63;
  int q = lane >> 4, l16 = lane & 15;
  int d = deg_dst[gw];
  int end = endp[gw], start = end - d;
  __half2 a0[4], a1[4];
  __half2 z = __floats2half2_rn(0.f, 0.f);
#pragma unroll
  for (int k = 0; k < 4; ++k) { a0[k] = z; a1[k] = z; }
  int i = start + q;
  for (; i + 4 < end; i += 8) {
    int r0 = ssrc[i], r1 = ssrc[i + 4];
    uint4 u0 = ((const uint4*)(xw + (size_t)r0 * KC))[l16];
    uint4 u1 = ((const uint4*)(xw + (size_t)r1 * KC))[l16];
    const __half2* p0 = (const __half2*)&u0;
    const __half2* p1 = (const __half2*)&u1;
#pragma unroll
    for (int k = 0; k < 4; ++k) {
      a0[k] = __hadd2(a0[k], p0[k]);
      a1[k] = __hadd2(a1[k], p1[k]);
    }
  }
  if (i < end) {
    int r = ssrc[i];
    uint4 u = ((const uint4*)(xw + (size_t)r * KC))[l16];
    const __half2* p = (const __half2*)&u;
#pragma unroll
    for (int k = 0; k < 4; ++k) a0[k] = __hadd2(a0[k], p[k]);
  }
  float f[8];
#pragma unroll
  for (int k = 0; k < 4; ++k) {
    float2 x0 = __half22float2(a0[k]);
    float2 x1 = __half22float2(a1[k]);
    f[2 * k] = x0.x + x1.x; f[2 * k + 1] = x0.y + x1.y;
  }
#pragma unroll
  for (int k = 0; k < 8; ++k) {
    f[k] += __shfl_xor(f[k], 16, 64);
    f[k] += __shfl_xor(f[k], 32, 64);
  }
  if (q == 0) {
    float invd = d > 0 ? rsqrtf((float)d) : 0.f;
    __half2 pk[4];
#pragma unroll
    for (int k = 0; k < 4; ++k)
      pk[k] = __floats2half2_rn(fmaxf(f[2 * k] * invd, 0.f),
                                fmaxf(f[2 * k + 1] * invd, 0.f));
    uint4 u;
    u.x = *(unsigned*)&pk[0]; u.y = *(unsigned*)&pk[1];
    u.z = *(unsigned*)&pk[2]; u.w = *(unsigned*)&pk[3];
    ((uint4*)(h + (size_t)gw * KC))[l16] = u;
  }
}

// ---- link scorer: quarter-wave per link ---------------------------------
__global__ void k_links(const __half* __restrict__ h,
                        const int* __restrict__ srcs, const int* __restrict__ dsts,
                        const float* __restrict__ Wp, const float* __restrict__ bp,
                        float* __restrict__ out, int L, int N) {
  int gw = (int)((blockIdx.x * blockDim.x + threadIdx.x) >> 6);
  int lane = threadIdx.x & 63;
  int q = lane >> 4, l16 = lane & 15;
  int li = gw * 4 + q;
  if (li >= L) return;
  int s = srcs[li], dd = dsts[li];
  const __half* hu = h + (size_t)N * KC;
  uint4 ua = ((const uint4*)(hu + (size_t)s * KC))[l16];
  uint4 ub = ((const uint4*)(h + (size_t)dd * KC))[l16];
  const __half2* pa = (const __half2*)&ua;
  const __half2* pb = (const __half2*)&ub;
  float acc = 0.f;
#pragma unroll
  for (int k = 0; k < 4; ++k) {
    float2 fa = __half22float2(pa[k]);
    float2 fb = __half22float2(pb[k]);
    float4 w = ((const float4*)Wp)[l16 * 4 + k];
    acc += fa.x * fb.x * (w.x + w.y) + fa.y * fb.y * (w.z + w.w);
  }
#pragma unroll
  for (int off = 8; off; off >>= 1) acc += __shfl_xor(acc, off, 64);
  if (l16 == 0) out[li] = acc + bp[0] + bp[1];
}

// ========================================================================
extern "C" void kernel_launch(void* const* d_in, const int* in_sizes, int n_in,
                              void* d_out, int out_size, void* d_ws, size_t ws_size,
                              hipStream_t stream) {
  const float* x_user = (const float*)d_in[0];
  const float* x_item = (const float*)d_in[1];
  const int*   edge_ui = (const int*)d_in[2];
  const int*   edge_iu = (const int*)d_in[3];
  const int*   elab    = (const int*)d_in[4];
  const float* p_ui   = (const float*)d_in[5];
  const float* W0_ui  = (const float*)d_in[6];
  const float* Wih_ui = (const float*)d_in[7];
  const float* Whh_ui = (const float*)d_in[8];
  const float* bih_ui = (const float*)d_in[9];
  const float* bhh_ui = (const float*)d_in[10];
  const float* p_iu   = (const float*)d_in[11];
  const float* W0_iu  = (const float*)d_in[12];
  const float* Wih_iu = (const float*)d_in[13];
  const float* Whh_iu = (const float*)d_in[14];
  const float* bih_iu = (const float*)d_in[15];
  const float* bhh_iu = (const float*)d_in[16];
  const float* W_post = (const float*)d_in[17];
  const float* b_post = (const float*)d_in[18];
  const int N = in_sizes[0] / KC;
  const int E = in_sizes[2] / 2;
  const int L = in_sizes[4] / 2;
  const int N2 = 2 * N;
  const int NBC = (N2 + CSZ - 1) >> CBITS;      // 40 coarse buckets
  const int chunk = (2 * E + NBLK - 1) / NBLK;  // 977
  const int NTOT = NBC * NBLK;                  // 81920 per segment
  const int SCB = (NTOT + 1023) / 1024;         // 80 scan blocks / segment

  char* wsp = (char*)d_ws;
  auto carve = [&](size_t bytes) -> void* {
    void* p = (void*)wsp;
    wsp += (bytes + 255) & ~(size_t)255;
    return p;
  };
  // zeroed region: hist[2*65536] | ctrl[16 u32]
  const size_t histB = 2 * 65536 * 4;
  const size_t zBytes = histB + 256;
  char*     zbase    = (char*)carve(zBytes);
  unsigned* hist     = (unsigned*)zbase;
  unsigned* ctrl     = (unsigned*)(zbase + histB);
  // non-zeroed scratch
  int*      deg_src  = (int*)carve((size_t)N2 * 4);
  __half*   x16      = (__half*)carve((size_t)N2 * KC * 2);
  __half*   xw       = (__half*)carve((size_t)N2 * KC * 2);
  __half*   h        = (__half*)carve((size_t)N2 * KC * 2);  // [h_item | h_user]
  float*    scores   = (float*)carve((size_t)N2 * 4);
  int*      cand_idx = (int*)carve(2 * 2048 * 4);
  float*    cand_val = (float*)carve(2 * 2048 * 4);
  int*      top_idx  = (int*)carve(2 * KC * 4);
  float*    top_tanh = (float*)carve(2 * KC * 4);
  __half*   Wt16     = (__half*)carve(2 * KC * KC * 2);
  unsigned* cnts     = (unsigned*)carve((size_t)2 * NTOT * 4);  // [dst | src]
  unsigned* sc       = (unsigned*)carve((size_t)2 * NTOT * 4);
  unsigned* bsum     = (unsigned*)carve((size_t)2 * SCB * 4);
  unsigned* recsD    = (unsigned*)carve((size_t)2 * E * 4);
  unsigned* recsS    = (unsigned*)carve((size_t)2 * E * 4);
  int*      ssrc     = (int*)carve((size_t)2 * E * 4);
  int*      deg_dst  = (int*)carve((size_t)N2 * 4);
  int*      endp     = (int*)carve((size_t)N2 * 4);

  hipMemsetAsync(zbase, 0, zBytes, stream);

  // scores + x16 (40K blocks, full occupancy)
  k_scores<<<(N2 + 3) / 4, 256, 0, stream>>>(x_user, x_item, p_ui, p_iu, scores, hist,
                                             x16, N);
  // graph sort: coarse counts -> scans -> fused partition -> refine
  k_cnt<<<NBLK, 256, 0, stream>>>(edge_ui, edge_iu, cnts, E, N, NBC, chunk, NTOT);
  k_scan1<<<2 * SCB, 1024, 0, stream>>>(cnts, sc, bsum, NTOT, NBC, SCB);
  k_scan2<<<2, 256, 0, stream>>>(bsum, SCB);
  k_part<<<NBLK, 256, 0, stream>>>(edge_ui, edge_iu, cnts, sc, bsum, recsD, recsS,
                                   E, N, NBC, chunk, NTOT, SCB);
  k_refine<<<2 * NBC, 1024, 0, stream>>>(sc, bsum, recsD, recsS, ssrc, deg_dst, endp,
                                         deg_src, E, NBC, N2, NTOT, SCB);

  // TopK pooling + GRU (X_tilde fused)
  k_thresh<<<2, 1024, 0, stream>>>(hist, ctrl);
  k_compact<<<(N2 + 255) / 256, 256, 0, stream>>>(scores, ctrl, cand_idx, cand_val, N);
  k_topk<<<2, 128, 0, stream>>>(ctrl, cand_idx, cand_val, p_ui, p_iu, top_idx, top_tanh);
  k_gru<<<2 * KC, KC, 0, stream>>>(x_user, x_item, top_idx, top_tanh,
                                   W0_ui, W0_iu, Wih_ui, Wih_iu, Whh_ui, Whh_iu,
                                   bih_ui, bih_iu, bhh_ui, bhh_iu, Wt16);

  // GCN: MFMA gemm (inv_s fused, fp16 out) then gather-aggregate
  k_gemm<<<N2 / 64, 256, 0, stream>>>(x16, Wt16, deg_src, xw, N);
  k_agg<<<(N2 + 3) / 4, 256, 0, stream>>>(xw, ssrc, endp, deg_dst, h, N2);
  // Link scorer
  k_links<<<((L + 3) / 4 + 3) / 4, 256, 0, stream>>>(h, elab, elab + L, W_post, b_post,
                                                     (float*)d_out, L, N);
}